// Round 22
// baseline (2119.032 us; speedup 1.0000x reference)
//
#include <hip/hip_runtime.h>
#include <hip/hip_bf16.h>

#define E_EDGES   800000
#define N_NODES   100000
#define HIDN      128
#define EDIMN     32
#define TILE      128                 // edges per block-iteration (4 waves x 32)
#define NT        (E_EDGES / TILE)    // 6250
#define GRID_MAIN 256
#define STR       35                  // stg row stride (f32)
#define NB_BLK    ((N_NODES + 1023) / 1024)

typedef __attribute__((ext_vector_type(8))) short bf16x8;
typedef __attribute__((ext_vector_type(4))) float f32x4;
typedef __attribute__((ext_vector_type(4))) unsigned int u32x4;

static __device__ __forceinline__ unsigned short f2bf(float f) {
  unsigned int u = __float_as_uint(f);
  u += 0x7fffu + ((u >> 16) & 1u);
  return (unsigned short)(u >> 16);
}
static __device__ __forceinline__ unsigned int pk2f(float a, float b) {
  __hip_bfloat162 h = __float22bfloat162_rn(make_float2(a, b));
  unsigned short lo = __hip_bfloat16_raw(h.x).x;
  unsigned short hi = __hip_bfloat16_raw(h.y).x;
  return (unsigned int)lo | ((unsigned int)hi << 16);
}
static __device__ __forceinline__ int swz(int row, int kElem) {
  return row * HIDN + (kElem ^ ((row & 7) << 3));
}
static __device__ __forceinline__ int swz32(int row, int kElem) {
  return row * EDIMN + (kElem ^ ((row & 3) << 3));
}
// k-permutation: hardware slot k_hw holds logical k = nmap(k_hw) (bijective)
static __device__ __forceinline__ int nmap(int k) {
  return ((k >> 5) << 5) | (((k & 7) >> 2) << 4) | (((k >> 3) & 3) << 2) | (k & 3);
}

template <bool RELU>
static __device__ __forceinline__ void packB(const f32x4* acc, bf16x8* B) {
#pragma unroll
  for (int ks = 0; ks < 4; ++ks) {
    f32x4 a = acc[2 * ks], b = acc[2 * ks + 1];
    if (RELU) {
#pragma unroll
      for (int j = 0; j < 4; ++j) { a[j] = fmaxf(a[j], 0.f); b[j] = fmaxf(b[j], 0.f); }
    }
    u32x4 t;
    t[0] = pk2f(a[0], a[1]); t[1] = pk2f(a[2], a[3]);
    t[2] = pk2f(b[0], b[1]); t[3] = pk2f(b[2], b[3]);
    union { u32x4 u; bf16x8 v; } cvt;
    cvt.u = t;
    B[ks] = cvt.v;
  }
}

static __device__ __forceinline__ void mmT(const unsigned short* W, f32x4* a0, f32x4* a1,
                                           const bf16x8* B0, const bf16x8* B1,
                                           int c16, int q) {
#pragma unroll
  for (int cb = 0; cb < 8; ++cb) {
#pragma unroll
    for (int ks = 0; ks < 4; ++ks) {
      bf16x8 w = *reinterpret_cast<const bf16x8*>(&W[swz(cb * 16 + c16, ks * 32 + q * 8)]);
      a0[cb] = __builtin_amdgcn_mfma_f32_16x16x32_bf16(w, B0[ks], a0[cb], 0, 0, 0);
      a1[cb] = __builtin_amdgcn_mfma_f32_16x16x32_bf16(w, B1[ks], a1[cb], 0, 0, 0);
    }
  }
}

__global__ void k_detect(const int* __restrict__ ei, int* __restrict__ flag) {
  __shared__ int nz;
  if (threadIdx.x == 0) nz = 0;
  __syncthreads();
  if (ei[2 * threadIdx.x + 1] != 0) atomicAdd(&nz, 1);
  __syncthreads();
  if (threadIdx.x == 0) flag[0] = (nz == 0) ? 1 : 0;   // 1 => int64
}

__global__ void k_norm(const int* __restrict__ ei, const int* __restrict__ flag,
                       int* __restrict__ idx) {
  const int stride = gridDim.x * blockDim.x;
  const int w = flag[0];
  for (int i = blockIdx.x * blockDim.x + threadIdx.x; i < 2 * E_EDGES; i += stride)
    idx[i] = w ? ei[2 * i] : ei[i];
}

__global__ void k_hist(const int* __restrict__ srcI, const int* __restrict__ dstI,
                       int* __restrict__ histD, int* __restrict__ histS) {
  const int stride = gridDim.x * blockDim.x;
  for (int e = blockIdx.x * blockDim.x + threadIdx.x; e < E_EDGES; e += stride) {
    atomicAdd(&histD[dstI[e]], 1);
    atomicAdd(&histS[srcI[e]], 1);
  }
}

__global__ void k_scan1(const int* __restrict__ in, int* __restrict__ out,
                        int* __restrict__ part, int n) {
  __shared__ int buf[1024];
  const int t = threadIdx.x;
  const int i = blockIdx.x * 1024 + t;
  int v = (i < n) ? in[i] : 0;
  buf[t] = v;
  __syncthreads();
  int acc = v;
  for (int off = 1; off < 1024; off <<= 1) {
    int add = (t >= off) ? buf[t - off] : 0;
    __syncthreads();
    acc += add;
    buf[t] = acc;
    __syncthreads();
  }
  if (i < n) out[i] = acc - v;                 // exclusive within block
  if (t == 1023) part[blockIdx.x] = acc;       // block total
}

__global__ void k_scan2(int* __restrict__ partD, int* __restrict__ partS, int nb) {
  if (threadIdx.x == 0) {
    int s = 0;
    for (int i = 0; i < nb; ++i) { int v = partD[i]; partD[i] = s; s += v; }
  }
  if (threadIdx.x == 1) {
    int s = 0;
    for (int i = 0; i < nb; ++i) { int v = partS[i]; partS[i] = s; s += v; }
  }
}

__global__ void k_scan3(int* __restrict__ base, int* __restrict__ cur,
                        const int* __restrict__ part, int n) {
  const int i = blockIdx.x * 1024 + threadIdx.x;
  if (i < n) {
    int b = base[i] + part[blockIdx.x];
    base[i] = b;
    cur[i] = b;
  }
}

__global__ void k_place(const int* __restrict__ srcI, const int* __restrict__ dstI,
                        int* __restrict__ curD, int* __restrict__ curS,
                        int* __restrict__ eF, int* __restrict__ gF, int* __restrict__ sF,
                        int* __restrict__ eB, int* __restrict__ gB, int* __restrict__ sB) {
  const int stride = gridDim.x * blockDim.x;
  for (int e = blockIdx.x * blockDim.x + threadIdx.x; e < E_EDGES; e += stride) {
    const int s = srcI[e], d = dstI[e];
    int p = atomicAdd(&curD[d], 1);
    eF[p] = e; gF[p] = s; sF[p] = d;
    int p2 = atomicAdd(&curS[s], 1);
    eB[p2] = e; gB[p2] = d; sB[p2] = s;
  }
}

__launch_bounds__(256, 1)
__global__ void k_conv(const float* __restrict__ x, const float* __restrict__ ea,
                       const int* __restrict__ eidx,
                       const int* __restrict__ gidx, const int* __restrict__ sidx,
                       const float* __restrict__ We1, const float* __restrict__ be1,
                       const float* __restrict__ We2, const float* __restrict__ be2,
                       const float* __restrict__ Wm1, const float* __restrict__ bm1,
                       const float* __restrict__ Wm2, const float* __restrict__ bm2,
                       const float* __restrict__ alphap, int dir,
                       float* __restrict__ out) {
  __shared__ unsigned short wt[3][HIDN * HIDN];   // We2,Wm1,Wm2*scale; [n][k_hw] swizzled, 96KB
  __shared__ unsigned short w1[HIDN * EDIMN];     // We1^T [n][k] swizzled, 8KB
  __shared__ float stg[4][32][STR];               // per-wave epilogue transpose, 17920B
  __shared__ float b1l[HIDN];                     // be1
  __shared__ float b3l[HIDN];                     // bm1 + be2 @ Wm1
  __shared__ float b4l[HIDN];                     // bm2 * scale

  const int tid = threadIdx.x;
  const int wv  = tid >> 6;
  const int ln  = tid & 63;
  const int q   = ln >> 4;
  const int c16 = ln & 15;

  const float sg    = 1.f / (1.f + expf(-alphap[0]));
  const float scale = dir ? (1.f - sg) : sg;

  {  // stage weights with k-permutation (coalesced over n)
    const float* Ws[3] = {We2, Wm1, Wm2};
    for (int m = 0; m < 3; ++m) {
      const float s = (m == 2) ? scale : 1.f;
      const float* W = Ws[m];
      for (int p = tid; p < HIDN * HIDN; p += 256) {
        int n = p & (HIDN - 1), k = p >> 7;
        wt[m][swz(n, k)] = f2bf(W[nmap(k) * HIDN + n] * s);
      }
    }
    for (int p = tid; p < HIDN * EDIMN; p += 256) {
      int n = p & (HIDN - 1), k = p >> 7;
      w1[swz32(n, k)] = f2bf(We1[k * HIDN + n]);
    }
    for (int n = tid; n < HIDN; n += 256) {
      b1l[n] = be1[n];
      b4l[n] = bm2[n] * scale;
      float acc = bm1[n];                          // fold be2 into stage-3 bias
      for (int k = 0; k < HIDN; ++k) acc += be2[k] * Wm1[k * HIDN + n];
      b3l[n] = acc;
    }
  }
  __syncthreads();

  const int o4 = q * 4;   // acc slot [cb][j] is feature n = 16cb + 4q + j
  const bool sorted = (eidx != nullptr);

  for (int t = blockIdx.x; t < NT; t += GRID_MAIN) {
    const int e0w = t * TILE + wv * 32;
    const int e_  = e0w + c16;

    const int ee0 = sorted ? eidx[e_] : e_;
    const int ee1 = sorted ? eidx[e_ + 16] : (e_ + 16);
    f32x4 e0a = *reinterpret_cast<const f32x4*>(&ea[(size_t)ee0 * EDIMN + q * 8]);
    f32x4 e0b = *reinterpret_cast<const f32x4*>(&ea[(size_t)ee0 * EDIMN + q * 8 + 4]);
    f32x4 e1a = *reinterpret_cast<const f32x4*>(&ea[(size_t)ee1 * EDIMN + q * 8]);
    f32x4 e1b = *reinterpret_cast<const f32x4*>(&ea[(size_t)ee1 * EDIMN + q * 8 + 4]);
    const int gi0 = gidx[e_], gi1 = gidx[e_ + 16];

    // scatter keys for the epilogue's row orientation (rows r = 16mb+4q+j)
    int sirC[2][4];
#pragma unroll
    for (int mb = 0; mb < 2; ++mb)
#pragma unroll
      for (int j = 0; j < 4; ++j)
        sirC[mb][j] = sidx[e0w + 16 * mb + 4 * q + j];

    f32x4 A0[8], A1[8];
    bf16x8 B0[4], B1[4];

    // ---- stage 1: relu(ea @ We1 + be1)
    {
      u32x4 t0, t1;
      t0[0] = pk2f(e0a[0], e0a[1]); t0[1] = pk2f(e0a[2], e0a[3]);
      t0[2] = pk2f(e0b[0], e0b[1]); t0[3] = pk2f(e0b[2], e0b[3]);
      t1[0] = pk2f(e1a[0], e1a[1]); t1[1] = pk2f(e1a[2], e1a[3]);
      t1[2] = pk2f(e1b[0], e1b[1]); t1[3] = pk2f(e1b[2], e1b[3]);
      union { u32x4 u; bf16x8 v; } c0, c1;
      c0.u = t0; c1.u = t1;
      bf16x8 E0 = c0.v;
      bf16x8 E1 = c1.v;
#pragma unroll
      for (int cb = 0; cb < 8; ++cb) {
        A0[cb] = *reinterpret_cast<const f32x4*>(&b1l[cb * 16 + o4]);
        A1[cb] = A0[cb];
      }
#pragma unroll
      for (int cb = 0; cb < 8; ++cb) {
        bf16x8 w = *reinterpret_cast<const bf16x8*>(&w1[swz32(cb * 16 + c16, q * 8)]);
        A0[cb] = __builtin_amdgcn_mfma_f32_16x16x32_bf16(w, E0, A0[cb], 0, 0, 0);
        A1[cb] = __builtin_amdgcn_mfma_f32_16x16x32_bf16(w, E1, A1[cb], 0, 0, 0);
      }
      packB<true>(A0, B0);
      packB<true>(A1, B1);
    }

    // ---- stage 2: Y1 @ We2 + x[g]
#pragma unroll
    for (int cb = 0; cb < 8; ++cb) {
      A0[cb] = *reinterpret_cast<const f32x4*>(&x[(size_t)gi0 * HIDN + cb * 16 + o4]);
      A1[cb] = *reinterpret_cast<const f32x4*>(&x[(size_t)gi1 * HIDN + cb * 16 + o4]);
    }
    mmT(&wt[0][0], A0, A1, B0, B1, c16, q);
    packB<false>(A0, B0);
    packB<false>(A1, B1);

    // ---- stage 3: relu(. @ Wm1 + b3eff)
#pragma unroll
    for (int cb = 0; cb < 8; ++cb) {
      A0[cb] = *reinterpret_cast<const f32x4*>(&b3l[cb * 16 + o4]);
      A1[cb] = A0[cb];
    }
    mmT(&wt[1][0], A0, A1, B0, B1, c16, q);
    packB<true>(A0, B0);
    packB<true>(A1, B1);

    // ---- stage 4: . @ (Wm2*scale) + bm2*scale
#pragma unroll
    for (int cb = 0; cb < 8; ++cb) {
      A0[cb] = *reinterpret_cast<const f32x4*>(&b4l[cb * 16 + o4]);
      A1[cb] = A0[cb];
    }
    mmT(&wt[2][0], A0, A1, B0, B1, c16, q);

    // ---- epilogue: LDS transpose -> plain coalesced per-row atomics (no segmentation)
#pragma unroll
    for (int p = 0; p < 4; ++p) {
#pragma unroll
      for (int cb2 = 0; cb2 < 2; ++cb2) {
        const int cb = 2 * p + cb2;
#pragma unroll
        for (int j = 0; j < 4; ++j) {
          stg[wv][c16][16 * cb2 + q + 4 * j]      = A0[cb][j];
          stg[wv][c16 + 16][16 * cb2 + q + 4 * j] = A1[cb][j];
        }
      }
      const int ca = c16 >> 2, cbt = c16 & 3;      // read perm: col C=16k+c16 -> 16k+4*cbt+ca
      // fixed-address LDS reads (all pipeline) + fire-and-forget atomics
      float v0[2][4], v1[2][4];
#pragma unroll
      for (int mb = 0; mb < 2; ++mb)
#pragma unroll
        for (int j = 0; j < 4; ++j) {
          const int r = 16 * mb + 4 * q + j;
          v0[mb][j] = stg[wv][r][4 * cbt + ca];
          v1[mb][j] = stg[wv][r][16 + 4 * cbt + ca];
        }
#pragma unroll
      for (int mb = 0; mb < 2; ++mb)
#pragma unroll
        for (int j = 0; j < 4; ++j) {
          float* po = out + (size_t)sirC[mb][j] * HIDN + 32 * p + c16;
          unsafeAtomicAdd(po, v0[mb][j]);
          unsafeAtomicAdd(po + 16, v1[mb][j]);
        }
    }
  }
}

extern "C" void kernel_launch(void* const* d_in, const int* in_sizes, int n_in,
                              void* d_out, int out_size, void* d_ws, size_t ws_size,
                              hipStream_t stream) {
  const float* x     = (const float*)d_in[0];
  const int*   ei    = (const int*)d_in[1];
  const float* ea    = (const float*)d_in[2];
  const float* alpha = (const float*)d_in[3];
  const float* fWe1 = (const float*)d_in[4],  *fbe1 = (const float*)d_in[5];
  const float* fWe2 = (const float*)d_in[6],  *fbe2 = (const float*)d_in[7];
  const float* fWm1 = (const float*)d_in[8],  *fbm1 = (const float*)d_in[9];
  const float* fWm2 = (const float*)d_in[10], *fbm2 = (const float*)d_in[11];
  const float* bWe1 = (const float*)d_in[12], *bbe1 = (const float*)d_in[13];
  const float* bWe2 = (const float*)d_in[14], *bbe2 = (const float*)d_in[15];
  const float* bWm1 = (const float*)d_in[16], *bbm1 = (const float*)d_in[17];
  const float* bWm2 = (const float*)d_in[18], *bbm2 = (const float*)d_in[19];
  float* out = (float*)d_out;

  char* w = (char*)d_ws;
  int* flag = (int*)w;

  const size_t BINS = 400000;                 // N_NODES * 4 bytes
  const size_t EB   = (size_t)E_EDGES * 4;
  const size_t need = 256 + 4 * BINS + 1024 + 8 * EB;   // ~27.2 MB
  const bool doSort = (ws_size >= need);

  hipMemsetAsync(d_out, 0, (size_t)out_size * sizeof(float), stream);
  k_detect<<<1, 256, 0, stream>>>(ei, flag);

  if (doSort) {
    size_t off = 256;
    int* histD = (int*)(w + off); off += BINS;
    int* histS = (int*)(w + off); off += BINS;
    int* baseD = (int*)(w + off); off += BINS;
    int* baseS = (int*)(w + off); off += BINS;
    int* partD = (int*)(w + off); off += 512;
    int* partS = (int*)(w + off); off += 512;
    int* srcI  = (int*)(w + off); off += EB;
    int* dstI  = (int*)(w + off); off += EB;
    int* eF    = (int*)(w + off); off += EB;
    int* gF    = (int*)(w + off); off += EB;
    int* sF    = (int*)(w + off); off += EB;
    int* eB2   = (int*)(w + off); off += EB;
    int* gB2   = (int*)(w + off); off += EB;
    int* sB2   = (int*)(w + off); off += EB;
    int* idx   = srcI;   // contiguous [src | dst]

    k_norm<<<2048, 256, 0, stream>>>(ei, flag, idx);
    hipMemsetAsync(histD, 0, 2 * BINS, stream);              // histD+histS contiguous
    k_hist<<<2048, 256, 0, stream>>>(srcI, dstI, histD, histS);
    k_scan1<<<NB_BLK, 1024, 0, stream>>>(histD, baseD, partD, N_NODES);
    k_scan1<<<NB_BLK, 1024, 0, stream>>>(histS, baseS, partS, N_NODES);
    k_scan2<<<1, 64, 0, stream>>>(partD, partS, NB_BLK);
    k_scan3<<<NB_BLK, 1024, 0, stream>>>(baseD, histD, partD, N_NODES);  // histD becomes curD
    k_scan3<<<NB_BLK, 1024, 0, stream>>>(baseS, histS, partS, N_NODES);  // histS becomes curS
    k_place<<<2048, 256, 0, stream>>>(srcI, dstI, histD, histS,
                                      eF, gF, sF, eB2, gB2, sB2);

    // forward: sorted by dst; gather x[src], scatter to dst
    k_conv<<<GRID_MAIN, 256, 0, stream>>>(x, ea, eF, gF, sF,
                                          fWe1, fbe1, fWe2, fbe2, fWm1, fbm1, fWm2, fbm2,
                                          alpha, 0, out);
    // backward: sorted by src; gather x[dst], scatter to src
    k_conv<<<GRID_MAIN, 256, 0, stream>>>(x, ea, eB2, gB2, sB2,
                                          bWe1, bbe1, bWe2, bbe2, bWm1, bbm1, bWm2, bbm2,
                                          alpha, 1, out);
  } else {
    int* idx  = (int*)(w + 256);
    int* srcI = idx;
    int* dstI = idx + E_EDGES;
    k_norm<<<2048, 256, 0, stream>>>(ei, flag, idx);
    k_conv<<<GRID_MAIN, 256, 0, stream>>>(x, ea, nullptr, srcI, dstI,
                                          fWe1, fbe1, fWe2, fbe2, fWm1, fbm1, fWm2, fbm2,
                                          alpha, 0, out);
    k_conv<<<GRID_MAIN, 256, 0, stream>>>(x, ea, nullptr, dstI, srcI,
                                          bWe1, bbe1, bWe2, bbe2, bWm1, bbm1, bWm2, bbm2,
                                          alpha, 1, out);
  }
}

// Round 23
// 875.510 us; speedup vs baseline: 2.4203x; 2.4203x over previous
//
#include <hip/hip_runtime.h>
#include <hip/hip_bf16.h>

#define E_EDGES   800000
#define N_NODES   100000
#define HIDN      128
#define EDIMN     32
#define TILE      256                 // edges per block-iteration (4 waves x 64)
#define NT        (E_EDGES / TILE)    // 3125
#define GRID_MAIN 256
#define STR       35                  // stg row stride (f32)
#define NB_BLK    ((N_NODES + 1023) / 1024)

typedef __attribute__((ext_vector_type(8))) short bf16x8;
typedef __attribute__((ext_vector_type(4))) float f32x4;
typedef __attribute__((ext_vector_type(4))) unsigned int u32x4;

static __device__ __forceinline__ unsigned short f2bf(float f) {
  unsigned int u = __float_as_uint(f);
  u += 0x7fffu + ((u >> 16) & 1u);
  return (unsigned short)(u >> 16);
}
static __device__ __forceinline__ unsigned int pk2f(float a, float b) {
  __hip_bfloat162 h = __float22bfloat162_rn(make_float2(a, b));
  unsigned short lo = __hip_bfloat16_raw(h.x).x;
  unsigned short hi = __hip_bfloat16_raw(h.y).x;
  return (unsigned int)lo | ((unsigned int)hi << 16);
}
static __device__ __forceinline__ int swz(int row, int kElem) {
  return row * HIDN + (kElem ^ ((row & 7) << 3));
}
static __device__ __forceinline__ int swz32(int row, int kElem) {
  return row * EDIMN + (kElem ^ ((row & 3) << 3));
}
// k-permutation: hardware slot k_hw holds logical k = nmap(k_hw) (bijective)
static __device__ __forceinline__ int nmap(int k) {
  return ((k >> 5) << 5) | (((k & 7) >> 2) << 4) | (((k >> 3) & 3) << 2) | (k & 3);
}

template <bool RELU>
static __device__ __forceinline__ void packB(const f32x4* acc, bf16x8* B) {
#pragma unroll
  for (int ks = 0; ks < 4; ++ks) {
    f32x4 a = acc[2 * ks], b = acc[2 * ks + 1];
    if (RELU) {
#pragma unroll
      for (int j = 0; j < 4; ++j) { a[j] = fmaxf(a[j], 0.f); b[j] = fmaxf(b[j], 0.f); }
    }
    u32x4 t;
    t[0] = pk2f(a[0], a[1]); t[1] = pk2f(a[2], a[3]);
    t[2] = pk2f(b[0], b[1]); t[3] = pk2f(b[2], b[3]);
    union { u32x4 u; bf16x8 v; } cvt;
    cvt.u = t;
    B[ks] = cvt.v;
  }
}

// 4-way GEMM step: one weight load feeds 4 edge-groups (2x fewer ds_reads, 4x ILP)
static __device__ __forceinline__ void mmT4(const unsigned short* W,
                                            f32x4* a0, f32x4* a1, f32x4* a2, f32x4* a3,
                                            const bf16x8* B0, const bf16x8* B1,
                                            const bf16x8* B2, const bf16x8* B3,
                                            int c16, int q) {
#pragma unroll
  for (int cb = 0; cb < 8; ++cb) {
#pragma unroll
    for (int ks = 0; ks < 4; ++ks) {
      bf16x8 w = *reinterpret_cast<const bf16x8*>(&W[swz(cb * 16 + c16, ks * 32 + q * 8)]);
      a0[cb] = __builtin_amdgcn_mfma_f32_16x16x32_bf16(w, B0[ks], a0[cb], 0, 0, 0);
      a1[cb] = __builtin_amdgcn_mfma_f32_16x16x32_bf16(w, B1[ks], a1[cb], 0, 0, 0);
      a2[cb] = __builtin_amdgcn_mfma_f32_16x16x32_bf16(w, B2[ks], a2[cb], 0, 0, 0);
      a3[cb] = __builtin_amdgcn_mfma_f32_16x16x32_bf16(w, B3[ks], a3[cb], 0, 0, 0);
    }
  }
}

__global__ void k_detect(const int* __restrict__ ei, int* __restrict__ flag) {
  __shared__ int nz;
  if (threadIdx.x == 0) nz = 0;
  __syncthreads();
  if (ei[2 * threadIdx.x + 1] != 0) atomicAdd(&nz, 1);
  __syncthreads();
  if (threadIdx.x == 0) flag[0] = (nz == 0) ? 1 : 0;   // 1 => int64
}

__global__ void k_norm(const int* __restrict__ ei, const int* __restrict__ flag,
                       int* __restrict__ idx) {
  const int stride = gridDim.x * blockDim.x;
  const int w = flag[0];
  for (int i = blockIdx.x * blockDim.x + threadIdx.x; i < 2 * E_EDGES; i += stride)
    idx[i] = w ? ei[2 * i] : ei[i];
}

__global__ void k_hist(const int* __restrict__ srcI, const int* __restrict__ dstI,
                       int* __restrict__ histD, int* __restrict__ histS) {
  const int stride = gridDim.x * blockDim.x;
  for (int e = blockIdx.x * blockDim.x + threadIdx.x; e < E_EDGES; e += stride) {
    atomicAdd(&histD[dstI[e]], 1);
    atomicAdd(&histS[srcI[e]], 1);
  }
}

__global__ void k_scan1(const int* __restrict__ in, int* __restrict__ out,
                        int* __restrict__ part, int n) {
  __shared__ int buf[1024];
  const int t = threadIdx.x;
  const int i = blockIdx.x * 1024 + t;
  int v = (i < n) ? in[i] : 0;
  buf[t] = v;
  __syncthreads();
  int acc = v;
  for (int off = 1; off < 1024; off <<= 1) {
    int add = (t >= off) ? buf[t - off] : 0;
    __syncthreads();
    acc += add;
    buf[t] = acc;
    __syncthreads();
  }
  if (i < n) out[i] = acc - v;                 // exclusive within block
  if (t == 1023) part[blockIdx.x] = acc;       // block total
}

__global__ void k_scan2(int* __restrict__ partD, int* __restrict__ partS, int nb) {
  if (threadIdx.x == 0) {
    int s = 0;
    for (int i = 0; i < nb; ++i) { int v = partD[i]; partD[i] = s; s += v; }
  }
  if (threadIdx.x == 1) {
    int s = 0;
    for (int i = 0; i < nb; ++i) { int v = partS[i]; partS[i] = s; s += v; }
  }
}

__global__ void k_scan3(int* __restrict__ base, int* __restrict__ cur,
                        const int* __restrict__ part, int n) {
  const int i = blockIdx.x * 1024 + threadIdx.x;
  if (i < n) {
    int b = base[i] + part[blockIdx.x];
    base[i] = b;
    cur[i] = b;
  }
}

__global__ void k_place(const int* __restrict__ srcI, const int* __restrict__ dstI,
                        int* __restrict__ curD, int* __restrict__ curS,
                        int* __restrict__ eF, int* __restrict__ gF, int* __restrict__ sF,
                        int* __restrict__ eB, int* __restrict__ gB, int* __restrict__ sB) {
  const int stride = gridDim.x * blockDim.x;
  for (int e = blockIdx.x * blockDim.x + threadIdx.x; e < E_EDGES; e += stride) {
    const int s = srcI[e], d = dstI[e];
    int p = atomicAdd(&curD[d], 1);
    eF[p] = e; gF[p] = s; sF[p] = d;
    int p2 = atomicAdd(&curS[s], 1);
    eB[p2] = e; gB[p2] = d; sB[p2] = s;
  }
}

__launch_bounds__(256, 1)
__global__ void k_conv(const float* __restrict__ x, const float* __restrict__ ea,
                       const int* __restrict__ eidx,
                       const int* __restrict__ gidx, const int* __restrict__ sidx,
                       const float* __restrict__ We1, const float* __restrict__ be1,
                       const float* __restrict__ We2, const float* __restrict__ be2,
                       const float* __restrict__ Wm1, const float* __restrict__ bm1,
                       const float* __restrict__ Wm2, const float* __restrict__ bm2,
                       const float* __restrict__ alphap, int dir,
                       float* __restrict__ out) {
  __shared__ unsigned short wt[3][HIDN * HIDN];   // We2,Wm1,Wm2*scale; [n][k_hw] swizzled, 96KB
  __shared__ unsigned short w1[HIDN * EDIMN];     // We1^T [n][k] swizzled, 8KB
  __shared__ float stg[4][32][STR];               // per-wave epilogue transpose, 17920B
  __shared__ float b1l[HIDN];                     // be1
  __shared__ float b3l[HIDN];                     // bm1 + be2 @ Wm1
  __shared__ float b4l[HIDN];                     // bm2 * scale

  const int tid = threadIdx.x;
  const int wv  = tid >> 6;
  const int ln  = tid & 63;
  const int q   = ln >> 4;
  const int c16 = ln & 15;

  const float sg    = 1.f / (1.f + expf(-alphap[0]));
  const float scale = dir ? (1.f - sg) : sg;

  {  // stage weights with k-permutation (coalesced over n)
    const float* Ws[3] = {We2, Wm1, Wm2};
    for (int m = 0; m < 3; ++m) {
      const float s = (m == 2) ? scale : 1.f;
      const float* W = Ws[m];
      for (int p = tid; p < HIDN * HIDN; p += 256) {
        int n = p & (HIDN - 1), k = p >> 7;
        wt[m][swz(n, k)] = f2bf(W[nmap(k) * HIDN + n] * s);
      }
    }
    for (int p = tid; p < HIDN * EDIMN; p += 256) {
      int n = p & (HIDN - 1), k = p >> 7;
      w1[swz32(n, k)] = f2bf(We1[k * HIDN + n]);
    }
    for (int n = tid; n < HIDN; n += 256) {
      b1l[n] = be1[n];
      b4l[n] = bm2[n] * scale;
      float acc = bm1[n];                          // fold be2 into stage-3 bias
      for (int k = 0; k < HIDN; ++k) acc += be2[k] * Wm1[k * HIDN + n];
      b3l[n] = acc;
    }
  }
  __syncthreads();

  const int o4 = q * 4;   // acc slot [cb][j] is feature n = 16cb + 4q + j
  const bool sorted = (eidx != nullptr);

  for (int t = blockIdx.x; t < NT; t += GRID_MAIN) {
    const int e0w = t * TILE + wv * 64;   // this wave's 64 edges
    const int e_  = e0w + c16;

    int eeL[4], giL[4];
#pragma unroll
    for (int g = 0; g < 4; ++g) {
      eeL[g] = sorted ? eidx[e_ + 16 * g] : (e_ + 16 * g);
      giL[g] = gidx[e_ + 16 * g];
    }

    // ---- run masks for the two 32-row groups
    const int rkLo = sidx[e0w + (ln & 31)];
    const int rnLo = sidx[e0w + (ln & 31) + ((ln & 31) < 31 ? 1 : 0)];
    const unsigned long long maskLo = __ballot((ln < 31) && (rkLo == rnLo));
    const int rkHi = sidx[e0w + 32 + (ln & 31)];
    const int rnHi = sidx[e0w + 32 + (ln & 31) + ((ln & 31) < 31 ? 1 : 0)];
    const unsigned long long maskHi = __ballot((ln < 31) && (rkHi == rnHi));

    // scatter keys: sirC[g][j] = key of global row 16g + 4q + j
    int sirC[4][4];
#pragma unroll
    for (int g = 0; g < 4; ++g)
#pragma unroll
      for (int j = 0; j < 4; ++j)
        sirC[g][j] = sidx[e0w + 16 * g + 4 * q + j];

    f32x4 A0[8], A1[8], A2[8], A3[8];
    bf16x8 B0[4], B1[4], B2[4], B3[4];

    // ---- stage 1: relu(ea @ We1 + be1)
    {
      bf16x8 E[4];
#pragma unroll
      for (int g = 0; g < 4; ++g) {
        f32x4 a = *reinterpret_cast<const f32x4*>(&ea[(size_t)eeL[g] * EDIMN + q * 8]);
        f32x4 b = *reinterpret_cast<const f32x4*>(&ea[(size_t)eeL[g] * EDIMN + q * 8 + 4]);
        u32x4 t0;
        t0[0] = pk2f(a[0], a[1]); t0[1] = pk2f(a[2], a[3]);
        t0[2] = pk2f(b[0], b[1]); t0[3] = pk2f(b[2], b[3]);
        union { u32x4 u; bf16x8 v; } c0; c0.u = t0; E[g] = c0.v;
      }
#pragma unroll
      for (int cb = 0; cb < 8; ++cb) {
        f32x4 bi = *reinterpret_cast<const f32x4*>(&b1l[cb * 16 + o4]);
        A0[cb] = bi; A1[cb] = bi; A2[cb] = bi; A3[cb] = bi;
      }
#pragma unroll
      for (int cb = 0; cb < 8; ++cb) {
        bf16x8 w = *reinterpret_cast<const bf16x8*>(&w1[swz32(cb * 16 + c16, q * 8)]);
        A0[cb] = __builtin_amdgcn_mfma_f32_16x16x32_bf16(w, E[0], A0[cb], 0, 0, 0);
        A1[cb] = __builtin_amdgcn_mfma_f32_16x16x32_bf16(w, E[1], A1[cb], 0, 0, 0);
        A2[cb] = __builtin_amdgcn_mfma_f32_16x16x32_bf16(w, E[2], A2[cb], 0, 0, 0);
        A3[cb] = __builtin_amdgcn_mfma_f32_16x16x32_bf16(w, E[3], A3[cb], 0, 0, 0);
      }
      packB<true>(A0, B0); packB<true>(A1, B1);
      packB<true>(A2, B2); packB<true>(A3, B3);
    }

    // ---- stage 2: Y1 @ We2 + x[g]
#pragma unroll
    for (int cb = 0; cb < 8; ++cb) {
      A0[cb] = *reinterpret_cast<const f32x4*>(&x[(size_t)giL[0] * HIDN + cb * 16 + o4]);
      A1[cb] = *reinterpret_cast<const f32x4*>(&x[(size_t)giL[1] * HIDN + cb * 16 + o4]);
      A2[cb] = *reinterpret_cast<const f32x4*>(&x[(size_t)giL[2] * HIDN + cb * 16 + o4]);
      A3[cb] = *reinterpret_cast<const f32x4*>(&x[(size_t)giL[3] * HIDN + cb * 16 + o4]);
    }
    mmT4(&wt[0][0], A0, A1, A2, A3, B0, B1, B2, B3, c16, q);
    packB<false>(A0, B0); packB<false>(A1, B1);
    packB<false>(A2, B2); packB<false>(A3, B3);

    // ---- stage 3: relu(. @ Wm1 + b3eff)
#pragma unroll
    for (int cb = 0; cb < 8; ++cb) {
      f32x4 bi = *reinterpret_cast<const f32x4*>(&b3l[cb * 16 + o4]);
      A0[cb] = bi; A1[cb] = bi; A2[cb] = bi; A3[cb] = bi;
    }
    mmT4(&wt[1][0], A0, A1, A2, A3, B0, B1, B2, B3, c16, q);
    packB<true>(A0, B0); packB<true>(A1, B1);
    packB<true>(A2, B2); packB<true>(A3, B3);

    // ---- stage 4: . @ (Wm2*scale) + bm2*scale
#pragma unroll
    for (int cb = 0; cb < 8; ++cb) {
      f32x4 bi = *reinterpret_cast<const f32x4*>(&b4l[cb * 16 + o4]);
      A0[cb] = bi; A1[cb] = bi; A2[cb] = bi; A3[cb] = bi;
    }
    mmT4(&wt[2][0], A0, A1, A2, A3, B0, B1, B2, B3, c16, q);

    // ---- epilogue: two 32-row groups, each = R20's segmented reduction
#pragma unroll
    for (int grp = 0; grp < 2; ++grp) {
      const unsigned long long mask = grp ? maskHi : maskLo;
      const f32x4* AA0 = grp ? A2 : A0;
      const f32x4* AA1 = grp ? A3 : A1;
      // run ends via bit ops
      int rend[2][4];
#pragma unroll
      for (int mb = 0; mb < 2; ++mb)
#pragma unroll
        for (int j = 0; j < 4; ++j) {
          const int r = 16 * mb + 4 * q + j;
          const bool head = (r == 0) || !((mask >> (r - 1)) & 1ull);
          int e = r;
          if (head)
            e = r + 1 + (int)__builtin_ctzll(~(mask >> r));
          rend[mb][j] = e;
        }
#pragma unroll
      for (int p = 0; p < 4; ++p) {
#pragma unroll
        for (int cb2 = 0; cb2 < 2; ++cb2) {
          const int cb = 2 * p + cb2;
#pragma unroll
          for (int j = 0; j < 4; ++j) {
            stg[wv][c16][16 * cb2 + q + 4 * j]      = AA0[cb][j];
            stg[wv][c16 + 16][16 * cb2 + q + 4 * j] = AA1[cb][j];
          }
        }
        const int ca = c16 >> 2, cbt = c16 & 3;    // read perm: col 16k+c16 -> 16k+4*cbt+ca
#pragma unroll
        for (int mb = 0; mb < 2; ++mb)
#pragma unroll
          for (int j = 0; j < 4; ++j) {
            const int r  = 16 * mb + 4 * q + j;
            const int re = rend[mb][j];
            if (re > r) {
              float acc0 = 0.f, acc1 = 0.f;
              for (int rr = r; rr < re; ++rr) {
                acc0 += stg[wv][rr][4 * cbt + ca];
                acc1 += stg[wv][rr][16 + 4 * cbt + ca];
              }
              float* po = out + (size_t)sirC[2 * grp + mb][j] * HIDN + 32 * p + c16;
              unsafeAtomicAdd(po, acc0);
              unsafeAtomicAdd(po + 16, acc1);
            }
          }
      }
    }
  }
}

extern "C" void kernel_launch(void* const* d_in, const int* in_sizes, int n_in,
                              void* d_out, int out_size, void* d_ws, size_t ws_size,
                              hipStream_t stream) {
  const float* x     = (const float*)d_in[0];
  const int*   ei    = (const int*)d_in[1];
  const float* ea    = (const float*)d_in[2];
  const float* alpha = (const float*)d_in[3];
  const float* fWe1 = (const float*)d_in[4],  *fbe1 = (const float*)d_in[5];
  const float* fWe2 = (const float*)d_in[6],  *fbe2 = (const float*)d_in[7];
  const float* fWm1 = (const float*)d_in[8],  *fbm1 = (const float*)d_in[9];
  const float* fWm2 = (const float*)d_in[10], *fbm2 = (const float*)d_in[11];
  const float* bWe1 = (const float*)d_in[12], *bbe1 = (const float*)d_in[13];
  const float* bWe2 = (const float*)d_in[14], *bbe2 = (const float*)d_in[15];
  const float* bWm1 = (const float*)d_in[16], *bbm1 = (const float*)d_in[17];
  const float* bWm2 = (const float*)d_in[18], *bbm2 = (const float*)d_in[19];
  float* out = (float*)d_out;

  char* w = (char*)d_ws;
  int* flag = (int*)w;

  const size_t BINS = 400000;                 // N_NODES * 4 bytes
  const size_t EB   = (size_t)E_EDGES * 4;
  const size_t need = 256 + 4 * BINS + 1024 + 8 * EB;   // ~27.2 MB
  const bool doSort = (ws_size >= need);

  hipMemsetAsync(d_out, 0, (size_t)out_size * sizeof(float), stream);
  k_detect<<<1, 256, 0, stream>>>(ei, flag);

  if (doSort) {
    size_t off = 256;
    int* histD = (int*)(w + off); off += BINS;
    int* histS = (int*)(w + off); off += BINS;
    int* baseD = (int*)(w + off); off += BINS;
    int* baseS = (int*)(w + off); off += BINS;
    int* partD = (int*)(w + off); off += 512;
    int* partS = (int*)(w + off); off += 512;
    int* srcI  = (int*)(w + off); off += EB;
    int* dstI  = (int*)(w + off); off += EB;
    int* eF    = (int*)(w + off); off += EB;
    int* gF    = (int*)(w + off); off += EB;
    int* sF    = (int*)(w + off); off += EB;
    int* eB2   = (int*)(w + off); off += EB;
    int* gB2   = (int*)(w + off); off += EB;
    int* sB2   = (int*)(w + off); off += EB;
    int* idx   = srcI;   // contiguous [src | dst]

    k_norm<<<2048, 256, 0, stream>>>(ei, flag, idx);
    hipMemsetAsync(histD, 0, 2 * BINS, stream);              // histD+histS contiguous
    k_hist<<<2048, 256, 0, stream>>>(srcI, dstI, histD, histS);
    k_scan1<<<NB_BLK, 1024, 0, stream>>>(histD, baseD, partD, N_NODES);
    k_scan1<<<NB_BLK, 1024, 0, stream>>>(histS, baseS, partS, N_NODES);
    k_scan2<<<1, 64, 0, stream>>>(partD, partS, NB_BLK);
    k_scan3<<<NB_BLK, 1024, 0, stream>>>(baseD, histD, partD, N_NODES);  // histD becomes curD
    k_scan3<<<NB_BLK, 1024, 0, stream>>>(baseS, histS, partS, N_NODES);  // histS becomes curS
    k_place<<<2048, 256, 0, stream>>>(srcI, dstI, histD, histS,
                                      eF, gF, sF, eB2, gB2, sB2);

    // forward: sorted by dst; gather x[src], pre-reduced scatter to dst
    k_conv<<<GRID_MAIN, 256, 0, stream>>>(x, ea, eF, gF, sF,
                                          fWe1, fbe1, fWe2, fbe2, fWm1, fbm1, fWm2, fbm2,
                                          alpha, 0, out);
    // backward: sorted by src; gather x[dst], pre-reduced scatter to src
    k_conv<<<GRID_MAIN, 256, 0, stream>>>(x, ea, eB2, gB2, sB2,
                                          bWe1, bbe1, bWe2, bbe2, bWm1, bbm1, bWm2, bbm2,
                                          alpha, 1, out);
  } else {
    int* idx  = (int*)(w + 256);
    int* srcI = idx;
    int* dstI = idx + E_EDGES;
    k_norm<<<2048, 256, 0, stream>>>(ei, flag, idx);
    k_conv<<<GRID_MAIN, 256, 0, stream>>>(x, ea, nullptr, srcI, dstI,
                                          fWe1, fbe1, fWe2, fbe2, fWm1, fbm1, fWm2, fbm2,
                                          alpha, 0, out);
    k_conv<<<GRID_MAIN, 256, 0, stream>>>(x, ea, nullptr, dstI, srcI,
                                          bWe1, bbe1, bWe2, bbe2, bWm1, bbm1, bWm2, bbm2,
                                          alpha, 1, out);
  }
}

// Round 26
// 875.279 us; speedup vs baseline: 2.4210x; 1.0003x over previous
//
#include <hip/hip_runtime.h>
#include <hip/hip_bf16.h>

#define E_EDGES   800000
#define N_NODES   100000
#define HIDN      128
#define EDIMN     32
#define TILE      256                 // edges per block-iteration (4 waves x 64)
#define NT        (E_EDGES / TILE)    // 3125
#define GRID_MAIN 256
#define STR       35                  // stg row stride (f32)
#define NB_BLK    ((N_NODES + 1023) / 1024)

typedef __attribute__((ext_vector_type(8))) short bf16x8;
typedef __attribute__((ext_vector_type(4))) float f32x4;
typedef __attribute__((ext_vector_type(4))) unsigned int u32x4;

static __device__ __forceinline__ unsigned short f2bf(float f) {
  unsigned int u = __float_as_uint(f);
  u += 0x7fffu + ((u >> 16) & 1u);
  return (unsigned short)(u >> 16);
}
static __device__ __forceinline__ unsigned int pk2f(float a, float b) {
  __hip_bfloat162 h = __float22bfloat162_rn(make_float2(a, b));
  unsigned short lo = __hip_bfloat16_raw(h.x).x;
  unsigned short hi = __hip_bfloat16_raw(h.y).x;
  return (unsigned int)lo | ((unsigned int)hi << 16);
}
static __device__ __forceinline__ int swz(int row, int kElem) {
  return row * HIDN + (kElem ^ ((row & 7) << 3));
}
static __device__ __forceinline__ int swz32(int row, int kElem) {
  return row * EDIMN + (kElem ^ ((row & 3) << 3));
}
// k-permutation: hardware slot k_hw holds logical k = nmap(k_hw) (bijective)
static __device__ __forceinline__ int nmap(int k) {
  return ((k >> 5) << 5) | (((k & 7) >> 2) << 4) | (((k >> 3) & 3) << 2) | (k & 3);
}

template <bool RELU>
static __device__ __forceinline__ void packB(const f32x4* acc, bf16x8* B) {
#pragma unroll
  for (int ks = 0; ks < 4; ++ks) {
    f32x4 a = acc[2 * ks], b = acc[2 * ks + 1];
    if (RELU) {
#pragma unroll
      for (int j = 0; j < 4; ++j) { a[j] = fmaxf(a[j], 0.f); b[j] = fmaxf(b[j], 0.f); }
    }
    u32x4 t;
    t[0] = pk2f(a[0], a[1]); t[1] = pk2f(a[2], a[3]);
    t[2] = pk2f(b[0], b[1]); t[3] = pk2f(b[2], b[3]);
    union { u32x4 u; bf16x8 v; } cvt;
    cvt.u = t;
    B[ks] = cvt.v;
  }
}

// 4-way GEMM step: one weight load feeds 4 edge-groups (2x fewer ds_reads, 4x ILP)
static __device__ __forceinline__ void mmT4(const unsigned short* W,
                                            f32x4* a0, f32x4* a1, f32x4* a2, f32x4* a3,
                                            const bf16x8* B0, const bf16x8* B1,
                                            const bf16x8* B2, const bf16x8* B3,
                                            int c16, int q) {
#pragma unroll
  for (int cb = 0; cb < 8; ++cb) {
#pragma unroll
    for (int ks = 0; ks < 4; ++ks) {
      bf16x8 w = *reinterpret_cast<const bf16x8*>(&W[swz(cb * 16 + c16, ks * 32 + q * 8)]);
      a0[cb] = __builtin_amdgcn_mfma_f32_16x16x32_bf16(w, B0[ks], a0[cb], 0, 0, 0);
      a1[cb] = __builtin_amdgcn_mfma_f32_16x16x32_bf16(w, B1[ks], a1[cb], 0, 0, 0);
      a2[cb] = __builtin_amdgcn_mfma_f32_16x16x32_bf16(w, B2[ks], a2[cb], 0, 0, 0);
      a3[cb] = __builtin_amdgcn_mfma_f32_16x16x32_bf16(w, B3[ks], a3[cb], 0, 0, 0);
    }
  }
}

__global__ void k_detect(const int* __restrict__ ei, int* __restrict__ flag) {
  __shared__ int nz;
  if (threadIdx.x == 0) nz = 0;
  __syncthreads();
  if (ei[2 * threadIdx.x + 1] != 0) atomicAdd(&nz, 1);
  __syncthreads();
  if (threadIdx.x == 0) flag[0] = (nz == 0) ? 1 : 0;   // 1 => int64
}

__global__ void k_norm(const int* __restrict__ ei, const int* __restrict__ flag,
                       int* __restrict__ idx) {
  const int stride = gridDim.x * blockDim.x;
  const int w = flag[0];
  for (int i = blockIdx.x * blockDim.x + threadIdx.x; i < 2 * E_EDGES; i += stride)
    idx[i] = w ? ei[2 * i] : ei[i];
}

__global__ void k_hist(const int* __restrict__ srcI, const int* __restrict__ dstI,
                       int* __restrict__ histD, int* __restrict__ histS) {
  const int stride = gridDim.x * blockDim.x;
  for (int e = blockIdx.x * blockDim.x + threadIdx.x; e < E_EDGES; e += stride) {
    atomicAdd(&histD[dstI[e]], 1);
    atomicAdd(&histS[srcI[e]], 1);
  }
}

__global__ void k_scan1(const int* __restrict__ in, int* __restrict__ out,
                        int* __restrict__ part, int n) {
  __shared__ int buf[1024];
  const int t = threadIdx.x;
  const int i = blockIdx.x * 1024 + t;
  int v = (i < n) ? in[i] : 0;
  buf[t] = v;
  __syncthreads();
  int acc = v;
  for (int off = 1; off < 1024; off <<= 1) {
    int add = (t >= off) ? buf[t - off] : 0;
    __syncthreads();
    acc += add;
    buf[t] = acc;
    __syncthreads();
  }
  if (i < n) out[i] = acc - v;                 // exclusive within block
  if (t == 1023) part[blockIdx.x] = acc;       // block total
}

__global__ void k_scan2(int* __restrict__ partD, int* __restrict__ partS, int nb) {
  if (threadIdx.x == 0) {
    int s = 0;
    for (int i = 0; i < nb; ++i) { int v = partD[i]; partD[i] = s; s += v; }
  }
  if (threadIdx.x == 1) {
    int s = 0;
    for (int i = 0; i < nb; ++i) { int v = partS[i]; partS[i] = s; s += v; }
  }
}

__global__ void k_scan3(int* __restrict__ base, int* __restrict__ cur,
                        const int* __restrict__ part, int n) {
  const int i = blockIdx.x * 1024 + threadIdx.x;
  if (i < n) {
    int b = base[i] + part[blockIdx.x];
    base[i] = b;
    cur[i] = b;
  }
}

__global__ void k_place(const int* __restrict__ srcI, const int* __restrict__ dstI,
                        int* __restrict__ curD, int* __restrict__ curS,
                        int* __restrict__ eF, int* __restrict__ gF, int* __restrict__ sF,
                        int* __restrict__ eB, int* __restrict__ gB, int* __restrict__ sB) {
  const int stride = gridDim.x * blockDim.x;
  for (int e = blockIdx.x * blockDim.x + threadIdx.x; e < E_EDGES; e += stride) {
    const int s = srcI[e], d = dstI[e];
    int p = atomicAdd(&curD[d], 1);
    eF[p] = e; gF[p] = s; sF[p] = d;
    int p2 = atomicAdd(&curS[s], 1);
    eB[p2] = e; gB[p2] = d; sB[p2] = s;
  }
}

__launch_bounds__(256, 1)
__global__ void k_conv(const float* __restrict__ x, const float* __restrict__ ea,
                       const int* __restrict__ eidx,
                       const int* __restrict__ gidx, const int* __restrict__ sidx,
                       const float* __restrict__ We1, const float* __restrict__ be1,
                       const float* __restrict__ We2, const float* __restrict__ be2,
                       const float* __restrict__ Wm1, const float* __restrict__ bm1,
                       const float* __restrict__ Wm2, const float* __restrict__ bm2,
                       const float* __restrict__ alphap, int dir,
                       float* __restrict__ out) {
  __shared__ unsigned short wt[3][HIDN * HIDN];   // We2,Wm1,Wm2*scale; [n][k_hw] swizzled, 96KB
  __shared__ unsigned short w1[HIDN * EDIMN];     // We1^T [n][k] swizzled, 8KB
  __shared__ float stg[4][32][STR];               // per-wave epilogue transpose, 17920B
  __shared__ float b1l[HIDN];                     // be1
  __shared__ float b3l[HIDN];                     // bm1 + be2 @ Wm1
  __shared__ float b4l[HIDN];                     // bm2 * scale

  const int tid = threadIdx.x;
  const int wv  = tid >> 6;
  const int ln  = tid & 63;
  const int q   = ln >> 4;
  const int c16 = ln & 15;

  const float sg    = 1.f / (1.f + expf(-alphap[0]));
  const float scale = dir ? (1.f - sg) : sg;

  {  // stage weights with k-permutation (coalesced over n)
    const float* Ws[3] = {We2, Wm1, Wm2};
    for (int m = 0; m < 3; ++m) {
      const float s = (m == 2) ? scale : 1.f;
      const float* W = Ws[m];
      for (int p = tid; p < HIDN * HIDN; p += 256) {
        int n = p & (HIDN - 1), k = p >> 7;
        wt[m][swz(n, k)] = f2bf(W[nmap(k) * HIDN + n] * s);
      }
    }
    for (int p = tid; p < HIDN * EDIMN; p += 256) {
      int n = p & (HIDN - 1), k = p >> 7;
      w1[swz32(n, k)] = f2bf(We1[k * HIDN + n]);
    }
    for (int n = tid; n < HIDN; n += 256) {
      b1l[n] = be1[n];
      b4l[n] = bm2[n] * scale;
      float acc = bm1[n];                          // fold be2 into stage-3 bias
      for (int k = 0; k < HIDN; ++k) acc += be2[k] * Wm1[k * HIDN + n];
      b3l[n] = acc;
    }
  }
  __syncthreads();

  const int o4 = q * 4;   // acc slot [cb][j] is feature n = 16cb + 4q + j
  const bool sorted = (eidx != nullptr);

  for (int t = blockIdx.x; t < NT; t += GRID_MAIN) {
    const int e0w = t * TILE + wv * 64;   // this wave's 64 edges
    const int e_  = e0w + c16;

    int eeL[4], giL[4];
#pragma unroll
    for (int g = 0; g < 4; ++g) {
      eeL[g] = sorted ? eidx[e_ + 16 * g] : (e_ + 16 * g);
      giL[g] = gidx[e_ + 16 * g];
    }

    // ---- run masks for the two 32-row groups
    const int rkLo = sidx[e0w + (ln & 31)];
    const int rnLo = sidx[e0w + (ln & 31) + ((ln & 31) < 31 ? 1 : 0)];
    const unsigned long long maskLo = __ballot((ln < 31) && (rkLo == rnLo));
    const int rkHi = sidx[e0w + 32 + (ln & 31)];
    const int rnHi = sidx[e0w + 32 + (ln & 31) + ((ln & 31) < 31 ? 1 : 0)];
    const unsigned long long maskHi = __ballot((ln < 31) && (rkHi == rnHi));

    // scatter keys: sirC[g][j] = key of global row 16g + 4q + j
    int sirC[4][4];
#pragma unroll
    for (int g = 0; g < 4; ++g)
#pragma unroll
      for (int j = 0; j < 4; ++j)
        sirC[g][j] = sidx[e0w + 16 * g + 4 * q + j];

    f32x4 A0[8], A1[8], A2[8], A3[8];
    bf16x8 B0[4], B1[4], B2[4], B3[4];

    // ---- stage 1: relu(ea @ We1 + be1)
    {
      bf16x8 E[4];
#pragma unroll
      for (int g = 0; g < 4; ++g) {
        f32x4 a = *reinterpret_cast<const f32x4*>(&ea[(size_t)eeL[g] * EDIMN + q * 8]);
        f32x4 b = *reinterpret_cast<const f32x4*>(&ea[(size_t)eeL[g] * EDIMN + q * 8 + 4]);
        u32x4 t0;
        t0[0] = pk2f(a[0], a[1]); t0[1] = pk2f(a[2], a[3]);
        t0[2] = pk2f(b[0], b[1]); t0[3] = pk2f(b[2], b[3]);
        union { u32x4 u; bf16x8 v; } c0; c0.u = t0; E[g] = c0.v;
      }
#pragma unroll
      for (int cb = 0; cb < 8; ++cb) {
        f32x4 bi = *reinterpret_cast<const f32x4*>(&b1l[cb * 16 + o4]);
        A0[cb] = bi; A1[cb] = bi; A2[cb] = bi; A3[cb] = bi;
      }
#pragma unroll
      for (int cb = 0; cb < 8; ++cb) {
        bf16x8 w = *reinterpret_cast<const bf16x8*>(&w1[swz32(cb * 16 + c16, q * 8)]);
        A0[cb] = __builtin_amdgcn_mfma_f32_16x16x32_bf16(w, E[0], A0[cb], 0, 0, 0);
        A1[cb] = __builtin_amdgcn_mfma_f32_16x16x32_bf16(w, E[1], A1[cb], 0, 0, 0);
        A2[cb] = __builtin_amdgcn_mfma_f32_16x16x32_bf16(w, E[2], A2[cb], 0, 0, 0);
        A3[cb] = __builtin_amdgcn_mfma_f32_16x16x32_bf16(w, E[3], A3[cb], 0, 0, 0);
      }
      packB<true>(A0, B0); packB<true>(A1, B1);
      packB<true>(A2, B2); packB<true>(A3, B3);
    }

    // ---- stage 2: Y1 @ We2 + x[g]
#pragma unroll
    for (int cb = 0; cb < 8; ++cb) {
      A0[cb] = *reinterpret_cast<const f32x4*>(&x[(size_t)giL[0] * HIDN + cb * 16 + o4]);
      A1[cb] = *reinterpret_cast<const f32x4*>(&x[(size_t)giL[1] * HIDN + cb * 16 + o4]);
      A2[cb] = *reinterpret_cast<const f32x4*>(&x[(size_t)giL[2] * HIDN + cb * 16 + o4]);
      A3[cb] = *reinterpret_cast<const f32x4*>(&x[(size_t)giL[3] * HIDN + cb * 16 + o4]);
    }
    mmT4(&wt[0][0], A0, A1, A2, A3, B0, B1, B2, B3, c16, q);
    packB<false>(A0, B0); packB<false>(A1, B1);
    packB<false>(A2, B2); packB<false>(A3, B3);

    // ---- stage 3: relu(. @ Wm1 + b3eff)
#pragma unroll
    for (int cb = 0; cb < 8; ++cb) {
      f32x4 bi = *reinterpret_cast<const f32x4*>(&b3l[cb * 16 + o4]);
      A0[cb] = bi; A1[cb] = bi; A2[cb] = bi; A3[cb] = bi;
    }
    mmT4(&wt[1][0], A0, A1, A2, A3, B0, B1, B2, B3, c16, q);
    packB<true>(A0, B0); packB<true>(A1, B1);
    packB<true>(A2, B2); packB<true>(A3, B3);

    // ---- stage 4: . @ (Wm2*scale) + bm2*scale
#pragma unroll
    for (int cb = 0; cb < 8; ++cb) {
      f32x4 bi = *reinterpret_cast<const f32x4*>(&b4l[cb * 16 + o4]);
      A0[cb] = bi; A1[cb] = bi; A2[cb] = bi; A3[cb] = bi;
    }
    mmT4(&wt[2][0], A0, A1, A2, A3, B0, B1, B2, B3, c16, q);

    // ---- epilogue: two 32-row groups, each = segmented reduction over sorted runs
#pragma unroll
    for (int grp = 0; grp < 2; ++grp) {
      const unsigned long long mask = grp ? maskHi : maskLo;
      const f32x4* AA0 = grp ? A2 : A0;
      const f32x4* AA1 = grp ? A3 : A1;
      // run ends via bit ops
      int rend[2][4];
#pragma unroll
      for (int mb = 0; mb < 2; ++mb)
#pragma unroll
        for (int j = 0; j < 4; ++j) {
          const int r = 16 * mb + 4 * q + j;
          const bool head = (r == 0) || !((mask >> (r - 1)) & 1ull);
          int e = r;
          if (head)
            e = r + 1 + (int)__builtin_ctzll(~(mask >> r));
          rend[mb][j] = e;
        }
#pragma unroll
      for (int p = 0; p < 4; ++p) {
#pragma unroll
        for (int cb2 = 0; cb2 < 2; ++cb2) {
          const int cb = 2 * p + cb2;
#pragma unroll
          for (int j = 0; j < 4; ++j) {
            stg[wv][c16][16 * cb2 + q + 4 * j]      = AA0[cb][j];
            stg[wv][c16 + 16][16 * cb2 + q + 4 * j] = AA1[cb][j];
          }
        }
        const int ca = c16 >> 2, cbt = c16 & 3;    // read perm: col 16k+c16 -> 16k+4*cbt+ca
#pragma unroll
        for (int mb = 0; mb < 2; ++mb)
#pragma unroll
          for (int j = 0; j < 4; ++j) {
            const int r  = 16 * mb + 4 * q + j;
            const int re = rend[mb][j];
            if (re > r) {
              float acc0 = 0.f, acc1 = 0.f;
              for (int rr = r; rr < re; ++rr) {
                acc0 += stg[wv][rr][4 * cbt + ca];
                acc1 += stg[wv][rr][16 + 4 * cbt + ca];
              }
              float* po = out + (size_t)sirC[2 * grp + mb][j] * HIDN + 32 * p + c16;
              unsafeAtomicAdd(po, acc0);
              unsafeAtomicAdd(po + 16, acc1);
            }
          }
      }
    }
  }
}

extern "C" void kernel_launch(void* const* d_in, const int* in_sizes, int n_in,
                              void* d_out, int out_size, void* d_ws, size_t ws_size,
                              hipStream_t stream) {
  const float* x     = (const float*)d_in[0];
  const int*   ei    = (const int*)d_in[1];
  const float* ea    = (const float*)d_in[2];
  const float* alpha = (const float*)d_in[3];
  const float* fWe1 = (const float*)d_in[4],  *fbe1 = (const float*)d_in[5];
  const float* fWe2 = (const float*)d_in[6],  *fbe2 = (const float*)d_in[7];
  const float* fWm1 = (const float*)d_in[8],  *fbm1 = (const float*)d_in[9];
  const float* fWm2 = (const float*)d_in[10], *fbm2 = (const float*)d_in[11];
  const float* bWe1 = (const float*)d_in[12], *bbe1 = (const float*)d_in[13];
  const float* bWe2 = (const float*)d_in[14], *bbe2 = (const float*)d_in[15];
  const float* bWm1 = (const float*)d_in[16], *bbm1 = (const float*)d_in[17];
  const float* bWm2 = (const float*)d_in[18], *bbm2 = (const float*)d_in[19];
  float* out = (float*)d_out;

  char* w = (char*)d_ws;
  int* flag = (int*)w;

  const size_t BINS = 400000;                 // N_NODES * 4 bytes
  const size_t EB   = (size_t)E_EDGES * 4;
  const size_t need = 256 + 4 * BINS + 1024 + 8 * EB;   // ~27.2 MB
  const bool doSort = (ws_size >= need);

  hipMemsetAsync(d_out, 0, (size_t)out_size * sizeof(float), stream);
  k_detect<<<1, 256, 0, stream>>>(ei, flag);

  if (doSort) {
    size_t off = 256;
    int* histD = (int*)(w + off); off += BINS;
    int* histS = (int*)(w + off); off += BINS;
    int* baseD = (int*)(w + off); off += BINS;
    int* baseS = (int*)(w + off); off += BINS;
    int* partD = (int*)(w + off); off += 512;
    int* partS = (int*)(w + off); off += 512;
    int* srcI  = (int*)(w + off); off += EB;
    int* dstI  = (int*)(w + off); off += EB;
    int* eF    = (int*)(w + off); off += EB;
    int* gF    = (int*)(w + off); off += EB;
    int* sF    = (int*)(w + off); off += EB;
    int* eB2   = (int*)(w + off); off += EB;
    int* gB2   = (int*)(w + off); off += EB;
    int* sB2   = (int*)(w + off); off += EB;
    int* idx   = srcI;   // contiguous [src | dst]

    k_norm<<<2048, 256, 0, stream>>>(ei, flag, idx);
    hipMemsetAsync(histD, 0, 2 * BINS, stream);              // histD+histS contiguous
    k_hist<<<2048, 256, 0, stream>>>(srcI, dstI, histD, histS);
    k_scan1<<<NB_BLK, 1024, 0, stream>>>(histD, baseD, partD, N_NODES);
    k_scan1<<<NB_BLK, 1024, 0, stream>>>(histS, baseS, partS, N_NODES);
    k_scan2<<<1, 64, 0, stream>>>(partD, partS, NB_BLK);
    k_scan3<<<NB_BLK, 1024, 0, stream>>>(baseD, histD, partD, N_NODES);  // histD becomes curD
    k_scan3<<<NB_BLK, 1024, 0, stream>>>(baseS, histS, partS, N_NODES);  // histS becomes curS
    k_place<<<2048, 256, 0, stream>>>(srcI, dstI, histD, histS,
                                      eF, gF, sF, eB2, gB2, sB2);

    // forward: sorted by dst; gather x[src], pre-reduced scatter to dst
    k_conv<<<GRID_MAIN, 256, 0, stream>>>(x, ea, eF, gF, sF,
                                          fWe1, fbe1, fWe2, fbe2, fWm1, fbm1, fWm2, fbm2,
                                          alpha, 0, out);
    // backward: sorted by src; gather x[dst], pre-reduced scatter to src
    k_conv<<<GRID_MAIN, 256, 0, stream>>>(x, ea, eB2, gB2, sB2,
                                          bWe1, bbe1, bWe2, bbe2, bWm1, bbm1, bWm2, bbm2,
                                          alpha, 1, out);
  } else {
    int* idx  = (int*)(w + 256);
    int* srcI = idx;
    int* dstI = idx + E_EDGES;
    k_norm<<<2048, 256, 0, stream>>>(ei, flag, idx);
    k_conv<<<GRID_MAIN, 256, 0, stream>>>(x, ea, nullptr, srcI, dstI,
                                          fWe1, fbe1, fWe2, fbe2, fWm1, fbm1, fWm2, fbm2,
                                          alpha, 0, out);
    k_conv<<<GRID_MAIN, 256, 0, stream>>>(x, ea, nullptr, dstI, srcI,
                                          bWe1, bbe1, bWe2, bbe2, bWm1, bbm1, bWm2, bbm2,
                                          alpha, 1, out);
  }
}